// Round 1
// baseline (269.056 us; speedup 1.0000x reference)
//
#include <hip/hip_runtime.h>
#include <hip/hip_bf16.h>

#define LOG2E 1.44269504088896340736f

typedef float f32x4 __attribute__((ext_vector_type(4)));
typedef short bf16x4 __attribute__((ext_vector_type(4)));

static __device__ __forceinline__ f32x4 mfma16x16x16_bf16(bf16x4 a, bf16x4 b, f32x4 c) {
#if __has_builtin(__builtin_amdgcn_mfma_f32_16x16x16bf16_1k)
    return __builtin_amdgcn_mfma_f32_16x16x16bf16_1k(a, b, c, 0, 0, 0);
#else
    f32x4 d;
    asm volatile("v_mfma_f32_16x16x16_bf16 %0, %1, %2, %3\n\ts_nop 7\n\ts_nop 7"
                 : "=v"(d) : "v"(a), "v"(b), "v"(c));
    return d;
#endif
}

static __device__ __forceinline__ float fast_exp2(float x) {
#if __has_builtin(__builtin_amdgcn_exp2f)
    return __builtin_amdgcn_exp2f(x);
#else
    return exp2f(x);
#endif
}

static __device__ __forceinline__ unsigned short f2bf(float x) {
    union { float f; unsigned u; } v; v.f = x;
    unsigned r = v.u + 0x7FFF + ((v.u >> 16) & 1);   // RNE
    return (unsigned short)(r >> 16);
}

// ---------------------------------------------------------------------------
// Kernel A: QKV projections + Wo bf16 conversion.
//   Qp [B][4096][16] bf16  (q*log2e, d 8..15 = 0)
//   Kp [B][4096][16] bf16  (d 8..15 = 0)
//   Vg [B][64][4096] bf16  (e-major)
//   Wob [64][64] bf16
// grid 256 blocks x 256 thr; thread -> (b, m, e-half)
// ---------------------------------------------------------------------------
__global__ __launch_bounds__(256) void qkv_kernel(
    const float* __restrict__ fq, const float* __restrict__ fkv,
    const float* __restrict__ Wq, const float* __restrict__ bq,
    const float* __restrict__ Wk, const float* __restrict__ bk,
    const float* __restrict__ Wv, const float* __restrict__ bv,
    const float* __restrict__ Wo,
    unsigned short* __restrict__ Qp, unsigned short* __restrict__ Kp,
    unsigned short* __restrict__ Vg, unsigned short* __restrict__ Wob)
{
    __shared__ float Wq_t[64 * 8];    // [c][d]
    __shared__ float Wk_t[64 * 8];    // [c][d]
    __shared__ float Wv_t[64 * 64];   // [c][e]
    __shared__ float bq_s[8], bk_s[8], bv_s[64];

    const int tid = threadIdx.x;

    #pragma unroll
    for (int j = 0; j < 2; ++j) {
        int i = tid * 2 + j;           // 512 elems
        int d = i >> 6, c = i & 63;
        Wq_t[c * 8 + d] = Wq[i];
        Wk_t[c * 8 + d] = Wk[i];
    }
    #pragma unroll
    for (int j = 0; j < 16; ++j) {
        int i = tid * 16 + j;          // 4096 elems
        Wv_t[(i & 63) * 64 + (i >> 6)] = Wv[i];
    }
    if (tid < 8)  { bq_s[tid] = bq[tid]; bk_s[tid] = bk[tid]; }
    if (tid < 64) { bv_s[tid] = bv[tid]; }
    __syncthreads();

    const int blk  = blockIdx.x;
    const int b    = blk >> 5;
    const int mblk = blk & 31;
    const int m    = mblk * 128 + (tid & 127);
    const int half = tid >> 7;

    const float* xqp = fq  + (b * 64) * 4096 + m;
    const float* xkp = fkv + (b * 64) * 4096 + m;

    float aq[8], ak[8];
    f32x4 av[8];
    #pragma unroll
    for (int d = 0; d < 8; ++d) { aq[d] = 0.f; ak[d] = 0.f; }
    #pragma unroll
    for (int e = 0; e < 8; ++e) av[e] = (f32x4){0.f, 0.f, 0.f, 0.f};

    for (int c = 0; c < 64; ++c) {
        float xk = xkp[c * 4096];
        float xq = xqp[c * 4096];
        const f32x4* wq4 = (const f32x4*)&Wq_t[c * 8];
        const f32x4* wk4 = (const f32x4*)&Wk_t[c * 8];
        #pragma unroll
        for (int u = 0; u < 2; ++u) {
            f32x4 wq = wq4[u], wk = wk4[u];
            #pragma unroll
            for (int j = 0; j < 4; ++j) {
                aq[u * 4 + j] += wq[j] * xq;
                ak[u * 4 + j] += wk[j] * xk;
            }
        }
        const f32x4* wv4 = (const f32x4*)&Wv_t[c * 64 + half * 32];
        #pragma unroll
        for (int e = 0; e < 8; ++e) av[e] += wv4[e] * xk;
    }

    if (half == 0) {
        unsigned short tq[8], tk[8];
        #pragma unroll
        for (int d = 0; d < 8; ++d) {
            tq[d] = f2bf((aq[d] + bq_s[d]) * LOG2E);
            tk[d] = f2bf(ak[d] + bk_s[d]);
        }
        int base = (b * 4096 + m) * 16;
        uint4 u0, uk0;
        u0.x  = (unsigned)tq[0] | ((unsigned)tq[1] << 16);
        u0.y  = (unsigned)tq[2] | ((unsigned)tq[3] << 16);
        u0.z  = (unsigned)tq[4] | ((unsigned)tq[5] << 16);
        u0.w  = (unsigned)tq[6] | ((unsigned)tq[7] << 16);
        uk0.x = (unsigned)tk[0] | ((unsigned)tk[1] << 16);
        uk0.y = (unsigned)tk[2] | ((unsigned)tk[3] << 16);
        uk0.z = (unsigned)tk[4] | ((unsigned)tk[5] << 16);
        uk0.w = (unsigned)tk[6] | ((unsigned)tk[7] << 16);
        uint4 zz = {0u, 0u, 0u, 0u};
        *(uint4*)(Qp + base)     = u0;
        *((uint4*)(Qp + base) + 1) = zz;
        *(uint4*)(Kp + base)     = uk0;
        *((uint4*)(Kp + base) + 1) = zz;
    }

    #pragma unroll
    for (int e = 0; e < 8; ++e) {
        #pragma unroll
        for (int j = 0; j < 4; ++j) {
            int eg = half * 32 + e * 4 + j;
            Vg[(b * 64 + eg) * 4096 + m] = f2bf(av[e][j] + bv_s[eg]);
        }
    }

    if (blk < 16) {
        int i = blk * 256 + tid;
        Wob[i] = f2bf(Wo[i]);
    }
}

// ---------------------------------------------------------------------------
// Kernel B: fused flash attention + Wo epilogue + residual. Zero LDS.
// Each wave owns 16 query rows (one MFMA column tile); lane's query n = lane&15.
// Swapped-operand MFMAs keep softmax fully in-register.
// grid 512 blocks x 256 thr (4 independent waves).
// ---------------------------------------------------------------------------
__global__ __launch_bounds__(256) void attn_kernel(
    const float* __restrict__ fq, const float* __restrict__ bo,
    const float* __restrict__ gamma_p,
    const unsigned short* __restrict__ Qp, const unsigned short* __restrict__ Kp,
    const unsigned short* __restrict__ Vg, const unsigned short* __restrict__ Wob,
    float* __restrict__ out)
{
    const int tid  = threadIdx.x;
    const int lane = tid & 63;
    const int w    = tid >> 6;
    const int r    = lane & 15;
    const int q4   = ((lane >> 4) & 3) * 4;
    const int blk  = blockIdx.x;
    const int b    = blk >> 6;
    const int nblk = blk & 63;
    const int n    = nblk * 64 + w * 16 + r;   // this lane's query row

    const float g = gamma_p[0];

    const bf16x4 qf = *(const bf16x4*)(Qp + (b * 4096 + n) * 16 + q4);

    const unsigned short* kpb = Kp + b * 4096 * 16;
    const unsigned short* vgb = Vg + b * 64 * 4096;

    const int kbase = r * 16 + q4;
    int vbase[4];
    #pragma unroll
    for (int et = 0; et < 4; ++et) vbase[et] = (et * 16 + r) * 4096 + q4;

    const f32x4 z4 = {0.f, 0.f, 0.f, 0.f};
    f32x4 acc[4] = {z4, z4, z4, z4};
    float mrun = -INFINITY, lrun = 0.f;

    for (int t = 0; t < 64; ++t) {
        const int m0 = t * 64;
        bf16x4 kf[4];
        #pragma unroll
        for (int mt = 0; mt < 4; ++mt)
            kf[mt] = *(const bf16x4*)(kpb + (m0 + mt * 16) * 16 + kbase);
        f32x4 sc[4];
        #pragma unroll
        for (int mt = 0; mt < 4; ++mt)
            sc[mt] = mfma16x16x16_bf16(kf[mt], qf, z4);

        // ---- online softmax (base 2; log2e folded into Q) ----
        float mx = sc[0][0];
        #pragma unroll
        for (int mt = 0; mt < 4; ++mt)
            #pragma unroll
            for (int j = 0; j < 4; ++j)
                mx = fmaxf(mx, sc[mt][j]);
        mx = fmaxf(mx, __shfl_xor(mx, 16));
        mx = fmaxf(mx, __shfl_xor(mx, 32));
        const float mnew  = fmaxf(mrun, mx);
        const float scale = fast_exp2(mrun - mnew);
        float p[16];
        float ps = 0.f;
        #pragma unroll
        for (int mt = 0; mt < 4; ++mt)
            #pragma unroll
            for (int j = 0; j < 4; ++j) {
                float e = fast_exp2(sc[mt][j] - mnew);
                p[mt * 4 + j] = e;
                ps += e;
            }
        ps += __shfl_xor(ps, 16);
        ps += __shfl_xor(ps, 32);
        lrun = lrun * scale + ps;
        mrun = mnew;
        if (__any(scale < 1.0f)) {
            #pragma unroll
            for (int et = 0; et < 4; ++et) acc[et] *= scale;
        }

        // ---- pack P to bf16 B-fragments (already in-layout) ----
        bf16x4 pw[4];
        #pragma unroll
        for (int mt = 0; mt < 4; ++mt) {
            bf16x4 tmp;
            #pragma unroll
            for (int j = 0; j < 4; ++j) tmp[j] = (short)f2bf(p[mt * 4 + j]);
            pw[mt] = tmp;
        }

        // ---- PV: out^T += V^T_tile * P^T ----
        const unsigned short* vp = vgb + m0;
        #pragma unroll
        for (int mt = 0; mt < 4; ++mt) {
            #pragma unroll
            for (int et = 0; et < 4; ++et) {
                bf16x4 vf = *(const bf16x4*)(vp + vbase[et] + mt * 16);
                acc[et] = mfma16x16x16_bf16(vf, pw[mt], acc[et]);
            }
        }
    }

    // ---- normalize + Wo epilogue + residual ----
    const float linv = 1.0f / lrun;
    bf16x4 ow[4];
    #pragma unroll
    for (int et = 0; et < 4; ++et) {
        acc[et] *= linv;
        bf16x4 tmp;
        #pragma unroll
        for (int j = 0; j < 4; ++j) tmp[j] = (short)f2bf(acc[et][j]);
        ow[et] = tmp;
    }
    #pragma unroll
    for (int ft = 0; ft < 4; ++ft) {
        f32x4 facc = z4;
        #pragma unroll
        for (int et = 0; et < 4; ++et) {
            bf16x4 wf = *(const bf16x4*)(Wob + (ft * 16 + r) * 64 + et * 16 + q4);
            facc = mfma16x16x16_bf16(wf, ow[et], facc);
        }
        #pragma unroll
        for (int j = 0; j < 4; ++j) {
            int f = ft * 16 + q4 + j;
            int idx = (b * 64 + f) * 4096 + n;
            out[idx] = g * (facc[j] + bo[f]) + fq[idx];
        }
    }
}

extern "C" void kernel_launch(void* const* d_in, const int* in_sizes, int n_in,
                              void* d_out, int out_size, void* d_ws, size_t ws_size,
                              hipStream_t stream) {
    const float* fq    = (const float*)d_in[0];
    const float* fkv   = (const float*)d_in[1];
    const float* Wq    = (const float*)d_in[2];
    const float* bq    = (const float*)d_in[3];
    const float* Wk    = (const float*)d_in[4];
    const float* bk    = (const float*)d_in[5];
    const float* Wv    = (const float*)d_in[6];
    const float* bv    = (const float*)d_in[7];
    const float* Wo    = (const float*)d_in[8];
    const float* bo    = (const float*)d_in[9];
    const float* gamma = (const float*)d_in[10];
    float* out = (float*)d_out;

    char* ws = (char*)d_ws;
    unsigned short* Vg  = (unsigned short*)ws;                    // 4 MB
    unsigned short* Qp  = (unsigned short*)(ws + (4u << 20));     // 1 MB
    unsigned short* Kp  = (unsigned short*)(ws + (5u << 20));     // 1 MB
    unsigned short* Wob = (unsigned short*)(ws + (6u << 20));     // 8 KB

    qkv_kernel<<<256, 256, 0, stream>>>(fq, fkv, Wq, bq, Wk, bk, Wv, bv, Wo,
                                        Qp, Kp, Vg, Wob);
    attn_kernel<<<512, 256, 0, stream>>>(fq, bo, gamma, Qp, Kp, Vg, Wob, out);
}

// Round 2
// 113.379 us; speedup vs baseline: 2.3731x; 2.3731x over previous
//
#include <hip/hip_runtime.h>
#include <hip/hip_bf16.h>

#define LOG2E 1.44269504088896340736f

typedef float f32x4 __attribute__((ext_vector_type(4)));
typedef short bf16x4 __attribute__((ext_vector_type(4)));

static __device__ __forceinline__ f32x4 mfma16x16x16_bf16(bf16x4 a, bf16x4 b, f32x4 c) {
#if __has_builtin(__builtin_amdgcn_mfma_f32_16x16x16bf16_1k)
    return __builtin_amdgcn_mfma_f32_16x16x16bf16_1k(a, b, c, 0, 0, 0);
#else
    f32x4 d;
    asm volatile("v_mfma_f32_16x16x16_bf16 %0, %1, %2, %3\n\ts_nop 7\n\ts_nop 7"
                 : "=v"(d) : "v"(a), "v"(b), "v"(c));
    return d;
#endif
}

static __device__ __forceinline__ float fast_exp2(float x) {
#if __has_builtin(__builtin_amdgcn_exp2f)
    return __builtin_amdgcn_exp2f(x);
#else
    return exp2f(x);
#endif
}

static __device__ __forceinline__ unsigned short f2bf(float x) {
    union { float f; unsigned u; } v; v.f = x;
    unsigned r = v.u + 0x7FFF + ((v.u >> 16) & 1);   // RNE
    return (unsigned short)(r >> 16);
}

static __device__ __forceinline__ float bf2f(unsigned short u) {
    union { unsigned u; float f; } v; v.u = ((unsigned)u) << 16;
    return v.f;
}

// ---------------------------------------------------------------------------
// Kernel A: QKV projections + Wo bf16 conversion.
//   Qp  [B][4096][16] bf16  (q*log2e, d 8..15 = 0)
//   Kp  [B][4096][16] bf16  (d 8..15 = 0)
//   Vt  [B][m/16][e/16][16][16] bf16  (tiled: e_in_16 major, m_in_16 minor)
//   Wob [64][64] bf16
// grid 256 blocks x 256 thr; thread -> (b, m, e-half)
// ---------------------------------------------------------------------------
__global__ __launch_bounds__(256) void qkv_kernel(
    const float* __restrict__ fq, const float* __restrict__ fkv,
    const float* __restrict__ Wq, const float* __restrict__ bq,
    const float* __restrict__ Wk, const float* __restrict__ bk,
    const float* __restrict__ Wv, const float* __restrict__ bv,
    const float* __restrict__ Wo,
    unsigned short* __restrict__ Qp, unsigned short* __restrict__ Kp,
    unsigned short* __restrict__ Vt, unsigned short* __restrict__ Wob)
{
    __shared__ float Wq_t[64 * 8];    // [c][d]
    __shared__ float Wk_t[64 * 8];    // [c][d]
    __shared__ float Wv_t[64 * 64];   // [c][e]
    __shared__ float bq_s[8], bk_s[8], bv_s[64];

    const int tid = threadIdx.x;

    #pragma unroll
    for (int j = 0; j < 2; ++j) {
        int i = tid * 2 + j;           // 512 elems
        int d = i >> 6, c = i & 63;
        Wq_t[c * 8 + d] = Wq[i];
        Wk_t[c * 8 + d] = Wk[i];
    }
    #pragma unroll
    for (int j = 0; j < 16; ++j) {
        int i = tid * 16 + j;          // 4096 elems
        Wv_t[(i & 63) * 64 + (i >> 6)] = Wv[i];
    }
    if (tid < 8)  { bq_s[tid] = bq[tid]; bk_s[tid] = bk[tid]; }
    if (tid < 64) { bv_s[tid] = bv[tid]; }
    __syncthreads();

    const int blk  = blockIdx.x;
    const int b    = blk >> 5;
    const int mblk = blk & 31;
    const int m    = mblk * 128 + (tid & 127);
    const int half = tid >> 7;

    const float* xqp = fq  + (b * 64) * 4096 + m;
    const float* xkp = fkv + (b * 64) * 4096 + m;

    float aq[8], ak[8];
    f32x4 av[8];
    #pragma unroll
    for (int d = 0; d < 8; ++d) { aq[d] = 0.f; ak[d] = 0.f; }
    #pragma unroll
    for (int e = 0; e < 8; ++e) av[e] = (f32x4){0.f, 0.f, 0.f, 0.f};

    for (int c = 0; c < 64; ++c) {
        float xk = xkp[c * 4096];
        float xq = xqp[c * 4096];
        const f32x4* wq4 = (const f32x4*)&Wq_t[c * 8];
        const f32x4* wk4 = (const f32x4*)&Wk_t[c * 8];
        #pragma unroll
        for (int u = 0; u < 2; ++u) {
            f32x4 wq = wq4[u], wk = wk4[u];
            #pragma unroll
            for (int j = 0; j < 4; ++j) {
                aq[u * 4 + j] += wq[j] * xq;
                ak[u * 4 + j] += wk[j] * xk;
            }
        }
        const f32x4* wv4 = (const f32x4*)&Wv_t[c * 64 + half * 32];
        #pragma unroll
        for (int e = 0; e < 8; ++e) av[e] += wv4[e] * xk;
    }

    if (half == 0) {
        unsigned short tq[8], tk[8];
        #pragma unroll
        for (int d = 0; d < 8; ++d) {
            tq[d] = f2bf((aq[d] + bq_s[d]) * LOG2E);
            tk[d] = f2bf(ak[d] + bk_s[d]);
        }
        int base = (b * 4096 + m) * 16;
        uint4 u0, uk0;
        u0.x  = (unsigned)tq[0] | ((unsigned)tq[1] << 16);
        u0.y  = (unsigned)tq[2] | ((unsigned)tq[3] << 16);
        u0.z  = (unsigned)tq[4] | ((unsigned)tq[5] << 16);
        u0.w  = (unsigned)tq[6] | ((unsigned)tq[7] << 16);
        uk0.x = (unsigned)tk[0] | ((unsigned)tk[1] << 16);
        uk0.y = (unsigned)tk[2] | ((unsigned)tk[3] << 16);
        uk0.z = (unsigned)tk[4] | ((unsigned)tk[5] << 16);
        uk0.w = (unsigned)tk[6] | ((unsigned)tk[7] << 16);
        uint4 zz = {0u, 0u, 0u, 0u};
        *(uint4*)(Qp + base)     = u0;
        *((uint4*)(Qp + base) + 1) = zz;
        *(uint4*)(Kp + base)     = uk0;
        *((uint4*)(Kp + base) + 1) = zz;
    }

    // V in tiled layout: Vt[((b*256 + m/16)*4 + e/16)*256 + (e%16)*16 + (m%16)]
    const int mt16 = m >> 4, mlo = m & 15;
    #pragma unroll
    for (int e = 0; e < 8; ++e) {
        #pragma unroll
        for (int j = 0; j < 4; ++j) {
            int eg = half * 32 + e * 4 + j;
            Vt[((b * 256 + mt16) * 4 + (eg >> 4)) * 256 + (eg & 15) * 16 + mlo]
                = f2bf(av[e][j] + bv_s[eg]);
        }
    }

    if (blk < 16) {
        int i = blk * 256 + tid;
        Wob[i] = f2bf(Wo[i]);
    }
}

// ---------------------------------------------------------------------------
// Kernel B: flash attention, split-M (flash-decoding). Zero LDS.
// grid 2048 blocks (seg[4] x b[8] x nblk[64]) x 256 thr.
// Each wave owns 16 query rows over a 1024-key segment; stores bf16 partial
// acc + (m,l) per row to workspace.
// ---------------------------------------------------------------------------
__global__ __launch_bounds__(256, 8) void attn_kernel(
    const unsigned short* __restrict__ Qp, const unsigned short* __restrict__ Kp,
    const unsigned short* __restrict__ Vt,
    unsigned short* __restrict__ accP, float* __restrict__ mlP)
{
    const int tid  = threadIdx.x;
    const int lane = tid & 63;
    const int w    = tid >> 6;
    const int r    = lane & 15;
    const int q4   = ((lane >> 4) & 3) * 4;
    const int id   = blockIdx.x;
    const int s    = id >> 9;          // segment 0..3
    const int g    = id & 511;         // b*64 + nblk
    const int b    = g >> 6;
    const int nblk = g & 63;
    const int n    = nblk * 64 + w * 16 + r;

    const bf16x4 qf = *(const bf16x4*)(Qp + (b * 4096 + n) * 16 + q4);

    const unsigned short* kpb = Kp + b * 4096 * 16;
    const unsigned short* vtb = Vt + b * 256 * 4 * 256;
    const int kbase = r * 16 + q4;
    const int vfrag = r * 16 + q4;

    const f32x4 z4 = {0.f, 0.f, 0.f, 0.f};
    f32x4 acc[4] = {z4, z4, z4, z4};
    float mrun = -INFINITY, lrun = 0.f;

    for (int t = s * 16; t < s * 16 + 16; ++t) {
        const int m0 = t * 64;
        bf16x4 kf[4];
        #pragma unroll
        for (int mt = 0; mt < 4; ++mt)
            kf[mt] = *(const bf16x4*)(kpb + (m0 + mt * 16) * 16 + kbase);
        f32x4 sc[4];
        #pragma unroll
        for (int mt = 0; mt < 4; ++mt)
            sc[mt] = mfma16x16x16_bf16(kf[mt], qf, z4);

        // ---- online softmax (base 2; log2e folded into Q) ----
        float mx = sc[0][0];
        #pragma unroll
        for (int mt = 0; mt < 4; ++mt)
            #pragma unroll
            for (int j = 0; j < 4; ++j)
                mx = fmaxf(mx, sc[mt][j]);
        mx = fmaxf(mx, __shfl_xor(mx, 16));
        mx = fmaxf(mx, __shfl_xor(mx, 32));
        const float mnew  = fmaxf(mrun, mx);
        const float scale = fast_exp2(mrun - mnew);
        float p[16];
        float ps = 0.f;
        #pragma unroll
        for (int mt = 0; mt < 4; ++mt)
            #pragma unroll
            for (int j = 0; j < 4; ++j) {
                float e = fast_exp2(sc[mt][j] - mnew);
                p[mt * 4 + j] = e;
                ps += e;
            }
        ps += __shfl_xor(ps, 16);
        ps += __shfl_xor(ps, 32);
        lrun = lrun * scale + ps;
        mrun = mnew;
        if (__any(scale < 1.0f)) {
            #pragma unroll
            for (int et = 0; et < 4; ++et) acc[et] *= scale;
        }

        // ---- pack P to bf16 B-fragments (already in-layout) ----
        bf16x4 pw[4];
        #pragma unroll
        for (int mt = 0; mt < 4; ++mt) {
            bf16x4 tmp;
            #pragma unroll
            for (int j = 0; j < 4; ++j) tmp[j] = (short)f2bf(p[mt * 4 + j]);
            pw[mt] = tmp;
        }

        // ---- PV: out^T += V^T_tile * P^T  (Vt tiles are 512B contiguous) ----
        #pragma unroll
        for (int mt = 0; mt < 4; ++mt) {
            const unsigned short* vp = vtb + ((t * 4 + mt) * 4) * 256 + vfrag;
            #pragma unroll
            for (int et = 0; et < 4; ++et) {
                bf16x4 vf = *(const bf16x4*)(vp + et * 256);
                acc[et] = mfma16x16x16_bf16(vf, pw[mt], acc[et]);
            }
        }
    }

    // ---- store partials (bf16 acc, f32 m/l) ----
    #pragma unroll
    for (int et = 0; et < 4; ++et) {
        bf16x4 tmp;
        #pragma unroll
        for (int j = 0; j < 4; ++j) tmp[j] = (short)f2bf(acc[et][j]);
        *(bf16x4*)(accP + (((((s * 512 + g) * 4 + w) * 4 + et) * 64 + lane) * 4)) = tmp;
    }
    if (lane < 16) {
        int mi = ((((s * 512 + g) * 4 + w) * 16) + r) * 2;
        mlP[mi]     = mrun;
        mlP[mi + 1] = lrun;
    }
}

// ---------------------------------------------------------------------------
// Kernel C: combine 4 segments + Wo epilogue + residual.
// grid 512 blocks (b[8] x nblk[64]) x 256 thr; same wave/lane layout as attn.
// ---------------------------------------------------------------------------
__global__ __launch_bounds__(256) void combine_kernel(
    const float* __restrict__ fq, const float* __restrict__ bo,
    const float* __restrict__ gamma_p,
    const unsigned short* __restrict__ accP, const float* __restrict__ mlP,
    const unsigned short* __restrict__ Wob, float* __restrict__ out)
{
    const int tid  = threadIdx.x;
    const int lane = tid & 63;
    const int w    = tid >> 6;
    const int r    = lane & 15;
    const int q4   = ((lane >> 4) & 3) * 4;
    const int g    = blockIdx.x;
    const int b    = g >> 6;
    const int nblk = g & 63;
    const int n    = nblk * 64 + w * 16 + r;

    const float gam = gamma_p[0];

    float m_s[4], l_s[4];
    #pragma unroll
    for (int s = 0; s < 4; ++s) {
        int mi = ((((s * 512 + g) * 4 + w) * 16) + r) * 2;
        m_s[s] = mlP[mi];
        l_s[s] = mlP[mi + 1];
    }
    float gm = fmaxf(fmaxf(m_s[0], m_s[1]), fmaxf(m_s[2], m_s[3]));
    float L = 0.f, wt[4];
    #pragma unroll
    for (int s = 0; s < 4; ++s) {
        wt[s] = fast_exp2(m_s[s] - gm);
        L += l_s[s] * wt[s];
    }

    const f32x4 z4 = {0.f, 0.f, 0.f, 0.f};
    f32x4 acc[4] = {z4, z4, z4, z4};
    #pragma unroll
    for (int s = 0; s < 4; ++s) {
        #pragma unroll
        for (int et = 0; et < 4; ++et) {
            bf16x4 a = *(const bf16x4*)(accP +
                (((((s * 512 + g) * 4 + w) * 4 + et) * 64 + lane) * 4));
            #pragma unroll
            for (int j = 0; j < 4; ++j)
                acc[et][j] += bf2f((unsigned short)a[j]) * wt[s];
        }
    }

    const float linv = 1.0f / L;
    bf16x4 ow[4];
    #pragma unroll
    for (int et = 0; et < 4; ++et) {
        acc[et] *= linv;
        bf16x4 tmp;
        #pragma unroll
        for (int j = 0; j < 4; ++j) tmp[j] = (short)f2bf(acc[et][j]);
        ow[et] = tmp;
    }
    #pragma unroll
    for (int ft = 0; ft < 4; ++ft) {
        f32x4 facc = z4;
        #pragma unroll
        for (int et = 0; et < 4; ++et) {
            bf16x4 wf = *(const bf16x4*)(Wob + (ft * 16 + r) * 64 + et * 16 + q4);
            facc = mfma16x16x16_bf16(wf, ow[et], facc);
        }
        #pragma unroll
        for (int j = 0; j < 4; ++j) {
            int f = ft * 16 + q4 + j;
            int idx = (b * 64 + f) * 4096 + n;
            out[idx] = gam * (facc[j] + bo[f]) + fq[idx];
        }
    }
}

extern "C" void kernel_launch(void* const* d_in, const int* in_sizes, int n_in,
                              void* d_out, int out_size, void* d_ws, size_t ws_size,
                              hipStream_t stream) {
    const float* fq    = (const float*)d_in[0];
    const float* fkv   = (const float*)d_in[1];
    const float* Wq    = (const float*)d_in[2];
    const float* bq    = (const float*)d_in[3];
    const float* Wk    = (const float*)d_in[4];
    const float* bk    = (const float*)d_in[5];
    const float* Wv    = (const float*)d_in[6];
    const float* bv    = (const float*)d_in[7];
    const float* Wo    = (const float*)d_in[8];
    const float* bo    = (const float*)d_in[9];
    const float* gamma = (const float*)d_in[10];
    float* out = (float*)d_out;

    char* ws = (char*)d_ws;
    unsigned short* Vt   = (unsigned short*)ws;                    // 4 MB
    unsigned short* Qp   = (unsigned short*)(ws + (4u  << 20));    // 1 MB
    unsigned short* Kp   = (unsigned short*)(ws + (5u  << 20));    // 1 MB
    unsigned short* Wob  = (unsigned short*)(ws + (6u  << 20));    // 8 KB
    unsigned short* accP = (unsigned short*)(ws + (7u  << 20));    // 16.78 MB
    float*          mlP  = (float*)         (ws + (24u << 20));    // 1 MB

    qkv_kernel<<<256, 256, 0, stream>>>(fq, fkv, Wq, bq, Wk, bk, Wv, bv, Wo,
                                        Qp, Kp, Vt, Wob);
    attn_kernel<<<2048, 256, 0, stream>>>(Qp, Kp, Vt, accP, mlP);
    combine_kernel<<<512, 256, 0, stream>>>(fq, bo, gamma, accP, mlP, Wob, out);
}